// Round 7
// baseline (94.610 us; speedup 1.0000x reference)
//
#include <hip/hip_runtime.h>

#define B_ 4
#define T_ 8
#define N_ 256
#define F_ 16
#define D_ 64
#define NP (D_/2)       // 32 pairs
#define CHUNK 8
#define NCH (N_/CHUNK)  // 32 -> main grid = 1024 blocks = 4/CU exactly

#define SC 2.8853900817779268f        // 2*log2(e): exp2(SC*x) = e^{2x}
#define LOG2E 1.4426950408889634f

typedef __attribute__((ext_vector_type(16))) float f32x16;

__device__ __forceinline__ float fast_exp2(float x) { return __builtin_amdgcn_exp2f(x); }
__device__ __forceinline__ float fast_rcp(float x)  { return __builtin_amdgcn_rcpf(x); }

// ---------------- prologue ----------------
// q-rows -> StreamQ[row][4*pr + {0,1,2,3}] = (eqa, eqb, L2E*2*w1*eqa, L2E*2*w0*eqb)
// k-rows -> EkT[bt][d][m] = exp2(SC*(k Wk + bk)_d)   (transposed for coalesced main loads)
__global__ __launch_bounds__(256)
void tattn_proj_kernel(const float* __restrict__ query,
                       const float* __restrict__ keys,
                       const float* __restrict__ Wq, const float* __restrict__ bq,
                       const float* __restrict__ Wk, const float* __restrict__ bk,
                       const float* __restrict__ wt,
                       float* __restrict__ StreamQ, float* __restrict__ EkT)
{
    const int tid = threadIdx.x;
    const int row = blockIdx.x * 4 + (tid >> 6);   // 4 rows (waves) per block
    const int j   = tid & 63;
    const int NQ  = B_ * N_;

    if (row < NQ) {
        const float* in = query + (size_t)row * F_;
        float acc = bq[j];
        #pragma unroll
        for (int f = 0; f < F_; ++f) acc = fmaf(in[f], Wq[f * D_ + j], acc);
        float eq = fast_exp2(acc * SC);
        float wpart = wt[j ^ 1];                   // partner weight
        float* qs = StreamQ + (size_t)row * (4 * NP);
        const int pr = j >> 1;
        if ((j & 1) == 0) {                        // eqa + A-slot
            qs[4 * pr + 0] = eq;
            qs[4 * pr + 2] = LOG2E * 2.0f * wpart * eq;   // A = L2E*2*w1*eqa
        } else {                                   // eqb + B-slot
            qs[4 * pr + 1] = eq;
            qs[4 * pr + 3] = LOG2E * 2.0f * wpart * eq;   // B = L2E*2*w0*eqb
        }
    } else {
        const int r  = row - NQ;                   // r = bt*N + n
        const int bt = r >> 8, n = r & (N_ - 1);
        const float* in = keys + (size_t)r * F_;
        float acc = bk[j];
        #pragma unroll
        for (int f = 0; f < F_; ++f) acc = fmaf(in[f], Wk[f * D_ + j], acc);
        EkT[((size_t)bt * D_ + j) * N_ + n] = fast_exp2(acc * SC);
    }
}

// ---------------- main ----------------
// score*L2E = WsumL - sum_pairs (C01 + A*ek0 + B*ek1) * rcp((1+eqa*ek0)(1+eqb*ek1))
// eq-stream: 2 batches x 4 s_load_dwordx16 per row. kreg: coalesced from EkT. C01: 32 VGPRs.
__global__ __launch_bounds__(256, 4)
void tattn_main_kernel(const float* __restrict__ StreamQ,
                       const float* __restrict__ EkT,
                       const float* __restrict__ wt,
                       float* __restrict__ out)
{
    __shared__ float pbuf[CHUNK][N_];   // 8 KB
    __shared__ float totL[CHUNK];

    const int tid = threadIdx.x;
    const int bid = blockIdx.x;
    const int ch  = bid % NCH;
    const int t   = (bid / NCH) % T_;
    const int b   = bid / (NCH * T_);
    const int n0  = ch * CHUNK;
    const int bt  = b * T_ + t;

    // Ek column for this thread's key m=tid: 64 coalesced dword loads
    float kreg[D_];
    {
        const float* kp = EkT + (size_t)bt * D_ * N_ + tid;
        #pragma unroll
        for (int d = 0; d < D_; ++d) kreg[d] = kp[(size_t)d * N_];
    }

    // C01[pr] = L2E*2*(w0+w1); uniform-address loads (1 line each), once per block
    float C01[NP];
    float Wsum = 0.f;
    #pragma unroll
    for (int pr = 0; pr < NP; ++pr) {
        float w0 = wt[2 * pr], w1 = wt[2 * pr + 1];
        C01[pr] = LOG2E * 2.0f * (w0 + w1);
        Wsum += w0 + w1;
    }
    const float WsumL = Wsum * LOG2E;

    const char* srow = (const char*)(StreamQ + ((size_t)(b * N_ + n0)) * (4 * NP)); // 512 B/row

#define DO4(EV, PRB)                                                        \
    {                                                                       \
        _Pragma("unroll")                                                   \
        for (int i = 0; i < 4; ++i) {                                       \
            const int pr = (PRB) + i;                                       \
            float eqa = EV[4*i+0], eqb = EV[4*i+1];                         \
            float A   = EV[4*i+2], Bv  = EV[4*i+3];                         \
            float pA = fmaf(eqa, kreg[2*pr+0], 1.0f);                       \
            float qA = fmaf(eqb, kreg[2*pr+1], 1.0f);                       \
            float nA = fmaf(A, kreg[2*pr+0], fmaf(Bv, kreg[2*pr+1], C01[pr])); \
            float r  = fast_rcp(pA * qA);                                   \
            if      ((pr & 3) == 0) a0 = fmaf(nA, r, a0);                   \
            else if ((pr & 3) == 1) a1 = fmaf(nA, r, a1);                   \
            else if ((pr & 3) == 2) a2 = fmaf(nA, r, a2);                   \
            else                    a3 = fmaf(nA, r, a3);                   \
        }                                                                   \
    }

    #pragma unroll 1
    for (int nn = 0; nn < CHUNK; ++nn) {
        float a0 = 0.f, a1 = 0.f, a2 = 0.f, a3 = 0.f;

        {   // batch 0: pairs 0..15 (256 B)
            f32x16 e0, e1, e2, e3;
            asm volatile("s_load_dwordx16 %0, %4, 0x0\n\t"
                         "s_load_dwordx16 %1, %4, 0x40\n\t"
                         "s_load_dwordx16 %2, %4, 0x80\n\t"
                         "s_load_dwordx16 %3, %4, 0xc0"
                         : "=&s"(e0), "=&s"(e1), "=&s"(e2), "=&s"(e3)
                         : "s"(srow));
            asm volatile("s_waitcnt lgkmcnt(0)"
                         : "+s"(e0), "+s"(e1), "+s"(e2), "+s"(e3));
            __builtin_amdgcn_sched_barrier(0);
            DO4(e0, 0) DO4(e1, 4) DO4(e2, 8) DO4(e3, 12)
        }
        {   // batch 1: pairs 16..31
            f32x16 e0, e1, e2, e3;
            asm volatile("s_load_dwordx16 %0, %4, 0x100\n\t"
                         "s_load_dwordx16 %1, %4, 0x140\n\t"
                         "s_load_dwordx16 %2, %4, 0x180\n\t"
                         "s_load_dwordx16 %3, %4, 0x1c0"
                         : "=&s"(e0), "=&s"(e1), "=&s"(e2), "=&s"(e3)
                         : "s"(srow));
            asm volatile("s_waitcnt lgkmcnt(0)"
                         : "+s"(e0), "+s"(e1), "+s"(e2), "+s"(e3));
            __builtin_amdgcn_sched_barrier(0);
            DO4(e0, 16) DO4(e1, 20) DO4(e2, 24) DO4(e3, 28)
        }

        // p = exp2(L2E*score); |score| small -> no max subtraction
        pbuf[nn][tid] = fast_exp2(WsumL - ((a0 + a1) + (a2 + a3)));
        srow += 4 * NP * sizeof(float);
    }
    __syncthreads();

    // per-row totals outside the hot loop: wave w reduces rows 2w, 2w+1
    const int lane = tid & 63;
    const int wid  = tid >> 6;
    #pragma unroll
    for (int rr = 0; rr < 2; ++rr) {
        const int row = wid * 2 + rr;
        float4 v = *reinterpret_cast<const float4*>(&pbuf[row][lane * 4]);
        float s = (v.x + v.y) + (v.z + v.w);
        #pragma unroll
        for (int off = 32; off >= 1; off >>= 1) s += __shfl_xor(s, off);
        if (lane == 0) totL[row] = s;
    }
    __syncthreads();

    const size_t obase = ((size_t)(bt * N_ + n0)) * N_ + tid;
    #pragma unroll
    for (int nn = 0; nn < CHUNK; ++nn)
        out[obase + (size_t)nn * N_] = pbuf[nn][tid] * fast_rcp(totL[nn]);
#undef DO4
}

extern "C" void kernel_launch(void* const* d_in, const int* in_sizes, int n_in,
                              void* d_out, int out_size, void* d_ws, size_t ws_size,
                              hipStream_t stream) {
    const float* query = (const float*)d_in[0];
    const float* keys  = (const float*)d_in[1];
    const float* Wq    = (const float*)d_in[2];
    const float* bq    = (const float*)d_in[3];
    const float* Wk    = (const float*)d_in[4];
    const float* bk    = (const float*)d_in[5];
    const float* wt    = (const float*)d_in[6];
    float* out = (float*)d_out;

    float* StreamQ = (float*)d_ws;                       // B*N*128 floats = 512 KB
    float* EkT     = StreamQ + (size_t)B_ * N_ * 4 * NP; // B*T*D*N floats = 2 MB

    const int rows = B_ * N_ + B_ * T_ * N_;             // 9216, 4 rows/block
    hipLaunchKernelGGL(tattn_proj_kernel, dim3(rows / 4), dim3(256), 0, stream,
                       query, keys, Wq, bq, Wk, bk, wt, StreamQ, EkT);

    hipLaunchKernelGGL(tattn_main_kernel, dim3(B_ * T_ * NCH), dim3(256), 0, stream,
                       StreamQ, EkT, wt, out);
}

// Round 8
// 30.779 us; speedup vs baseline: 3.0738x; 3.0738x over previous
//
#include <hip/hip_runtime.h>

#define B_ 4
#define T_ 8
#define N_ 256
#define F_ 16
#define D_ 64
#define NP (D_/2)       // 32 pairs per row
#define CHUNK 8
#define NCH (N_/CHUNK)  // 32 -> main grid = 1024 blocks

#define SC 2.8853900817779268f        // 2*log2(e): exp2(SC*x) = e^{2x}
#define LOG2E 1.4426950408889634f

typedef __attribute__((ext_vector_type(16))) float f32x16;

__device__ __forceinline__ float fast_exp2(float x) { return __builtin_amdgcn_exp2f(x); }
__device__ __forceinline__ float fast_rcp(float x)  { return __builtin_amdgcn_rcpf(x); }

// ---------------- prologue ----------------
// Eq[row][d] = exp2(SC*(q Wq + bq)_d)               (row-major, coalesced)
// EkT[bt][d][m] = exp2(SC*(k Wk + bk)_d)            (TRANSPOSED for coalesced main loads)
__global__ __launch_bounds__(256)
void tattn_proj_kernel(const float* __restrict__ query,
                       const float* __restrict__ keys,
                       const float* __restrict__ Wq, const float* __restrict__ bq,
                       const float* __restrict__ Wk, const float* __restrict__ bk,
                       float* __restrict__ Eq, float* __restrict__ EkT)
{
    const int tid = threadIdx.x;
    const int row = blockIdx.x * 4 + (tid >> 6);   // 4 rows (waves) per block
    const int j   = tid & 63;
    const int NQ  = B_ * N_;

    if (row < NQ) {                                // wave-uniform branch
        const float* in = query + (size_t)row * F_;
        float acc = bq[j];
        #pragma unroll
        for (int f = 0; f < F_; ++f) acc = fmaf(in[f], Wq[f * D_ + j], acc);
        Eq[(size_t)row * D_ + j] = fast_exp2(acc * SC);
    } else {
        const int r  = row - NQ;                   // r = bt*N + n
        const int bt = r >> 8, n = r & (N_ - 1);
        const float* in = keys + (size_t)r * F_;
        float acc = bk[j];
        #pragma unroll
        for (int f = 0; f < F_; ++f) acc = fmaf(in[f], Wk[f * D_ + j], acc);
        EkT[((size_t)bt * D_ + j) * N_ + n] = fast_exp2(acc * SC);
    }
}

// ---------------- main ----------------
// score(n,m) = Wsum - sum_pairs (2w0(1+x1)+2w1(1+x0)) * rcp((1+x0)(1+x1)), x_d = eq_d*ek_d
// eq: 4x s_load_dwordx16 -> SGPRs (one drain/row). wt: replicated VGPRs. ek: coalesced VGPRs.
// Hot loop: zero LDS, zero VMEM.
__global__ __launch_bounds__(256, 3)
void tattn_main_kernel(const float* __restrict__ Eq,
                       const float* __restrict__ EkT,
                       const float* __restrict__ wt,
                       float* __restrict__ out)
{
    __shared__ float pbuf[CHUNK][N_];   // 8 KB
    __shared__ float wls[D_];           // 2*wt staging
    __shared__ float totL[CHUNK];

    const int tid = threadIdx.x;
    const int bid = blockIdx.x;
    const int ch  = bid % NCH;
    const int t   = (bid / NCH) % T_;
    const int b   = bid / (NCH * T_);
    const int n0  = ch * CHUNK;
    const int bt  = b * T_ + t;

    if (tid < D_) wls[tid] = 2.0f * wt[tid];

    // Ek column for this thread's key m=tid: 64 fully-coalesced wave loads
    float kreg[D_];
    {
        const float* kp = EkT + (size_t)bt * D_ * N_ + tid;
        #pragma unroll
        for (int d = 0; d < D_; ++d) kreg[d] = kp[(size_t)d * N_];
    }
    __syncthreads();

    // 2*wt into VGPRs via LDS reads (ds_read dest is always a VGPR -> stays vector-side)
    float wv[D_];
    #pragma unroll
    for (int d = 0; d < D_; d += 4) {
        float4 v = *reinterpret_cast<const float4*>(&wls[d]);
        wv[d] = v.x; wv[d+1] = v.y; wv[d+2] = v.z; wv[d+3] = v.w;
    }
    float Wsum = 0.f;
    #pragma unroll
    for (int d = 0; d < D_; ++d) Wsum += wv[d];
    Wsum *= 0.5f;

    const float* eqrow = Eq + ((size_t)(b * N_ + n0)) * D_;   // advances 256 B/row

    #pragma unroll 1
    for (int nn = 0; nn < CHUNK; ++nn) {
        f32x16 e0, e1, e2, e3;
        asm volatile("s_load_dwordx16 %0, %4, 0x0\n\t"
                     "s_load_dwordx16 %1, %4, 0x40\n\t"
                     "s_load_dwordx16 %2, %4, 0x80\n\t"
                     "s_load_dwordx16 %3, %4, 0xc0"
                     : "=&s"(e0), "=&s"(e1), "=&s"(e2), "=&s"(e3)
                     : "s"(eqrow));
        asm volatile("s_waitcnt lgkmcnt(0)"
                     : "+s"(e0), "+s"(e1), "+s"(e2), "+s"(e3));
        __builtin_amdgcn_sched_barrier(0);

        float a0 = 0.f, a1 = 0.f, a2 = 0.f, a3 = 0.f;
        #pragma unroll
        for (int pr = 0; pr < NP; ++pr) {
            float eqa, eqb;
            if      (pr <  8) { eqa = e0[2*pr];      eqb = e0[2*pr+1];      }
            else if (pr < 16) { eqa = e1[2*pr-16];   eqb = e1[2*pr-15];     }
            else if (pr < 24) { eqa = e2[2*pr-32];   eqb = e2[2*pr-31];     }
            else              { eqa = e3[2*pr-48];   eqb = e3[2*pr-47];     }
            float pA = fmaf(eqa, kreg[2*pr+0], 1.0f);   // 1 + x0   (1 SGPR operand)
            float qA = fmaf(eqb, kreg[2*pr+1], 1.0f);   // 1 + x1
            float nA = fmaf(wv[2*pr+1], pA, wv[2*pr] * qA);  // all-VGPR
            float r  = fast_rcp(pA * qA);
            if      ((pr & 3) == 0) a0 = fmaf(nA, r, a0);
            else if ((pr & 3) == 1) a1 = fmaf(nA, r, a1);
            else if ((pr & 3) == 2) a2 = fmaf(nA, r, a2);
            else                    a3 = fmaf(nA, r, a3);
        }
        float score = Wsum - ((a0 + a1) + (a2 + a3));

        // |score| <= sum|wt| ~ 8 -> no max subtraction needed
        pbuf[nn][tid] = fast_exp2(score * LOG2E);
        eqrow += D_;
    }
    __syncthreads();

    // per-row totals: wave w reduces rows 2w, 2w+1 (outside hot loop)
    const int lane = tid & 63;
    const int wid  = tid >> 6;
    #pragma unroll
    for (int rr = 0; rr < 2; ++rr) {
        const int row = wid * 2 + rr;
        float4 v = *reinterpret_cast<const float4*>(&pbuf[row][lane * 4]);
        float s = (v.x + v.y) + (v.z + v.w);
        #pragma unroll
        for (int off = 32; off >= 1; off >>= 1) s += __shfl_xor(s, off);
        if (lane == 0) totL[row] = s;
    }
    __syncthreads();

    const size_t obase = ((size_t)(bt * N_ + n0)) * N_ + tid;
    #pragma unroll
    for (int nn = 0; nn < CHUNK; ++nn)
        out[obase + (size_t)nn * N_] = pbuf[nn][tid] * fast_rcp(totL[nn]);
}

extern "C" void kernel_launch(void* const* d_in, const int* in_sizes, int n_in,
                              void* d_out, int out_size, void* d_ws, size_t ws_size,
                              hipStream_t stream) {
    const float* query = (const float*)d_in[0];
    const float* keys  = (const float*)d_in[1];
    const float* Wq    = (const float*)d_in[2];
    const float* bq    = (const float*)d_in[3];
    const float* Wk    = (const float*)d_in[4];
    const float* bk    = (const float*)d_in[5];
    const float* wt    = (const float*)d_in[6];
    float* out = (float*)d_out;

    float* Eq  = (float*)d_ws;                         // B*N*D   = 65536 floats (256 KB)
    float* EkT = Eq + (size_t)B_ * N_ * D_;            // B*T*D*N = 524288 floats (2 MB)

    const int rows = B_ * N_ + B_ * T_ * N_;           // 9216, 4 rows/block
    hipLaunchKernelGGL(tattn_proj_kernel, dim3(rows / 4), dim3(256), 0, stream,
                       query, keys, Wq, bq, Wk, bk, Eq, EkT);

    hipLaunchKernelGGL(tattn_main_kernel, dim3(B_ * T_ * NCH), dim3(256), 0, stream,
                       Eq, EkT, wt, out);
}